// Round 13
// baseline (129.557 us; speedup 1.0000x reference)
//
#include <hip/hip_runtime.h>
#include <stdint.h>

#define EPS 1e-8f

typedef __attribute__((ext_vector_type(8))) __bf16 bf16x8;
typedef __attribute__((ext_vector_type(4))) float f32x4;

static constexpr int BO = 6400;   // B*O
static constexpr int AA = 16;     // attributes
static constexpr int DD = 1024;   // D
static constexpr int HH = 512;    // H

// ---------- helpers ----------
__device__ __forceinline__ unsigned short f2bf(float x) {
    uint32_t b = __float_as_uint(x);
    b += 0x7fffu + ((b >> 16) & 1u);   // round-to-nearest-even (finite inputs)
    return (unsigned short)(b >> 16);
}

__device__ __forceinline__ float fast_tanh(float x) {
    float e = __expf(2.0f * x);
    return 1.0f - __fdividef(2.0f, e + 1.0f);
}

// ---------- kernel 1: f32 -> bf16 staging of W_obj only ----------
__global__ __launch_bounds__(256) void k_prep_w(const float* __restrict__ W,
                                                unsigned short* __restrict__ W_bf) {
    const int i = blockIdx.x * 256 + threadIdx.x;   // 65536 8-elem units
    const long off = (long)i * 8;
    float4 v0 = *(const float4*)(W + off);
    float4 v1 = *(const float4*)(W + off + 4);
    union { unsigned short u[8]; int4 v; } pk;
    pk.u[0] = f2bf(v0.x); pk.u[1] = f2bf(v0.y); pk.u[2] = f2bf(v0.z); pk.u[3] = f2bf(v0.w);
    pk.u[4] = f2bf(v1.x); pk.u[5] = f2bf(v1.y); pk.u[6] = f2bf(v1.z); pk.u[7] = f2bf(v1.w);
    *(int4*)(W_bf + off) = pk.v;
}

// ---------- kernel 2: att_obj = obj @ W^T + b_obj, f32 out (round-3 verbatim) ----------
__global__ __launch_bounds__(64) void k_gemm(const float* __restrict__ obj,
                                             const unsigned short* __restrict__ W_bf,
                                             const float* __restrict__ b_obj,
                                             float* __restrict__ att_obj) {
    const int lane = threadIdx.x;
    const int xcd  = blockIdx.x & 7;
    const int j    = blockIdx.x >> 3;
    const int mt   = xcd * 13 + (j % 13);
    if (mt >= 100) return;
    const int nt   = j / 13;
    const int m0   = mt * 64;
    const int n0   = nt * 64;
    const int lr   = lane & 15;
    const int lk   = (lane >> 4) * 8;

    const float*          ap = obj  + (size_t)(m0 + lr) * DD + lk;
    const unsigned short* bp = W_bf + (size_t)(n0 + lr) * DD + lk;

    f32x4 acc[4][4];
    #pragma unroll
    for (int i = 0; i < 4; ++i)
        #pragma unroll
        for (int jj = 0; jj < 4; ++jj) acc[i][jj] = f32x4{0.f, 0.f, 0.f, 0.f};

    float4 a_lo[4], a_hi[4];
    bf16x8 bfr[4];
    #pragma unroll
    for (int i = 0; i < 4; ++i) {
        a_lo[i] = *(const float4*)(ap + (size_t)i * 16 * DD);
        a_hi[i] = *(const float4*)(ap + (size_t)i * 16 * DD + 4);
        bfr[i]  = *(const bf16x8*)(bp + (size_t)i * 16 * DD);
    }

    #pragma unroll 1
    for (int k0 = 0; k0 < DD; k0 += 32) {
        const int kn = (k0 + 32 < DD) ? (k0 + 32) : 0;
        float4 na_lo[4], na_hi[4];
        bf16x8 nb[4];
        #pragma unroll
        for (int i = 0; i < 4; ++i) {
            na_lo[i] = *(const float4*)(ap + (size_t)i * 16 * DD + kn);
            na_hi[i] = *(const float4*)(ap + (size_t)i * 16 * DD + kn + 4);
            nb[i]    = *(const bf16x8*)(bp + (size_t)i * 16 * DD + kn);
        }
        bf16x8 afr[4];
        #pragma unroll
        for (int i = 0; i < 4; ++i) {
            afr[i][0] = (__bf16)a_lo[i].x; afr[i][1] = (__bf16)a_lo[i].y;
            afr[i][2] = (__bf16)a_lo[i].z; afr[i][3] = (__bf16)a_lo[i].w;
            afr[i][4] = (__bf16)a_hi[i].x; afr[i][5] = (__bf16)a_hi[i].y;
            afr[i][6] = (__bf16)a_hi[i].z; afr[i][7] = (__bf16)a_hi[i].w;
        }
        #pragma unroll
        for (int i = 0; i < 4; ++i)
            #pragma unroll
            for (int jj = 0; jj < 4; ++jj)
                acc[i][jj] = __builtin_amdgcn_mfma_f32_16x16x32_bf16(afr[i], bfr[jj], acc[i][jj], 0, 0, 0);
        #pragma unroll
        for (int i = 0; i < 4; ++i) { a_lo[i] = na_lo[i]; a_hi[i] = na_hi[i]; bfr[i] = nb[i]; }
    }

    const int crow = (lane >> 4) * 4;
    #pragma unroll
    for (int jj = 0; jj < 4; ++jj) {
        const int n = n0 + jj * 16 + lr;
        const float bb = b_obj[n];
        #pragma unroll
        for (int i = 0; i < 4; ++i) {
            #pragma unroll
            for (int r = 0; r < 4; ++r)
                att_obj[(size_t)(m0 + i * 16 + crow + r) * HH + n] = acc[i][jj][r] + bb;
        }
    }
}

// ---------- kernel 3: fused attn — BROADCAST-ADDRESS mask skip ----------
// ONE WAVE PER ROW, 4 rows/block, no LDS/barriers, __launch_bounds__(256,5) —
// r10's exact structure (proven to saturate the per-CU memory pipe at ~10 B/cyc).
// 12-round model: the ceiling is CACHELINE SERVICE at the CU (hit or miss cost the
// same — r10's L1-hit redirect == r9's all-miss calib). A per-lane f32x4 wave-load
// touches 16 lines; a LANE-INVARIANT one touches 1. So masked attrs' loads select
// a broadcast address (base of attr a0's row): same instruction count, same
// registers, same schedule as r10 — but ~45% fewer lines serviced.
// Masked values are finite garbage * exact-0.0 weight = 0 (r10-validated numerics).
__global__ __launch_bounds__(256, 5) void k_attn(const float* __restrict__ att_obj,   // [6400][512] f32
                                                 const float* __restrict__ p_attr,    // [6400][16][512]
                                                 const int* __restrict__ masks,       // [6400][16]
                                                 const float* __restrict__ w_alpha,   // [512]
                                                 const float* __restrict__ attr_feats,// [6400][16][1024]
                                                 float* __restrict__ out) {           // [6400][1024]
    const int wv   = threadIdx.x >> 6;
    const int lane = threadIdx.x & 63;
    const int row  = blockIdx.x * 4 + wv;

    // masks -> 1-VGPR bitmask; a0 = first unmasked attr (broadcast target)
    int mbits;
    {
        const int4* m4 = (const int4*)(masks + (size_t)row * AA);
        int4 a = m4[0], b = m4[1], c = m4[2], d = m4[3];
        mbits =  (a.x)      | (a.y << 1)  | (a.z << 2)  | (a.w << 3)
              | (b.x << 4) | (b.y << 5)  | (b.z << 6)  | (b.w << 7)
              | (c.x << 8) | (c.y << 9)  | (c.z << 10) | (c.w << 11)
              | (d.x << 12)| (d.y << 13) | (d.z << 14) | (d.w << 15);
    }
    const int a0 = mbits ? __builtin_ctz(mbits) : 0;

    const float* prow = p_attr     + (size_t)row * AA * HH;
    const float* arow = attr_feats + (size_t)row * AA * DD;
    const f32x4* pbc  = (const f32x4*)(prow + (size_t)a0 * HH);   // lane-invariant
    const f32x4* abc  = (const f32x4*)(arow + (size_t)a0 * DD);   // lane-invariant

    // phase 1: per-attr partial dot; masked attrs read ONE broadcast line
    float sc[AA];
    {
        const f32x4* att4 = (const f32x4*)(att_obj + (size_t)row * HH);
        const f32x4* wa4  = (const f32x4*)w_alpha;
        const f32x4 av0 = att4[lane], av1 = att4[64 + lane];
        const f32x4 wv0 = wa4[lane],  wv1 = wa4[64 + lane];

        #pragma unroll 2
        for (int a = 0; a < AA; ++a) {
            const bool on = (mbits >> a) & 1;
            const f32x4* pa = (const f32x4*)(prow + (size_t)a * HH);
            f32x4 x0 = *(on ? pa +      lane : pbc);   // address select, 1 load
            f32x4 x1 = *(on ? pa + 64 + lane : pbc);
            float s;
            s  = wv0.x * fast_tanh(x0.x + av0.x);
            s += wv0.y * fast_tanh(x0.y + av0.y);
            s += wv0.z * fast_tanh(x0.z + av0.z);
            s += wv0.w * fast_tanh(x0.w + av0.w);
            s += wv1.x * fast_tanh(x1.x + av1.x);
            s += wv1.y * fast_tanh(x1.y + av1.y);
            s += wv1.z * fast_tanh(x1.z + av1.z);
            s += wv1.w * fast_tanh(x1.w + av1.w);
            sc[a] = s;
        }
    }

    // cross-lane butterfly (all 16, static; masked lanes' garbage discarded below)
    #pragma unroll
    for (int d = 1; d < 64; d <<= 1) {
        #pragma unroll
        for (int a = 0; a < AA; ++a) sc[a] += __shfl_xor(sc[a], d);
    }

    // phase 2: softmax over unmasked + renorm, in place (b_alpha cancels;
    // masked e == 0 -> denom = T*(1+EPS); all-masked -> inv = 0 -> out = 0 exact)
    float mx = -3.0e38f;
    #pragma unroll
    for (int a = 0; a < AA; ++a)
        if (mbits >> a & 1) mx = fmaxf(mx, sc[a]);
    float T = 0.f;
    #pragma unroll
    for (int a = 0; a < AA; ++a) {
        float e = (mbits >> a & 1) ? __expf(sc[a] - mx) : 0.f;
        sc[a] = e;
        T += e;
    }
    const float inv = (T > 0.f) ? 1.0f / (T * (1.0f + EPS)) : 0.f;
    #pragma unroll
    for (int a = 0; a < AA; ++a) sc[a] *= inv;

    // phase 3: streaming weighted pooling; masked attrs read ONE broadcast line
    f32x4 acc0 = {0.f,0.f,0.f,0.f}, acc1 = acc0, acc2 = acc0, acc3 = acc0;
    #pragma unroll 2
    for (int a = 0; a < AA; ++a) {
        const bool on = (mbits >> a) & 1;
        const f32x4* a4 = (const f32x4*)(arow + (size_t)a * DD);
        f32x4 v0 = *(on ? a4 +       lane : abc);
        f32x4 v1 = *(on ? a4 +  64 + lane : abc);
        f32x4 v2 = *(on ? a4 + 128 + lane : abc);
        f32x4 v3 = *(on ? a4 + 192 + lane : abc);
        const float w = sc[a];        // exact 0.0 for masked
        acc0 += w * v0;
        acc1 += w * v1;
        acc2 += w * v2;
        acc3 += w * v3;
    }
    f32x4* o4 = (f32x4*)(out + (size_t)row * DD);
    o4[      lane] = acc0;
    o4[ 64 + lane] = acc1;
    o4[128 + lane] = acc2;
    o4[192 + lane] = acc3;
}

extern "C" void kernel_launch(void* const* d_in, const int* in_sizes, int n_in,
                              void* d_out, int out_size, void* d_ws, size_t ws_size,
                              hipStream_t stream) {
    const float* obj_vecs   = (const float*)d_in[0];
    const float* attr_feats = (const float*)d_in[1];
    const float* p_attr     = (const float*)d_in[2];
    const int*   masks      = (const int*)d_in[3];
    const float* W_obj      = (const float*)d_in[4];
    const float* b_obj      = (const float*)d_in[5];
    const float* w_alpha    = (const float*)d_in[6];
    // d_in[7] = b_alpha: uniform additive shift before softmax -> cancels exactly
    float* out = (float*)d_out;

    char* ws = (char*)d_ws;
    float*          att_obj = (float*)ws;                       // 13,107,200 B
    unsigned short* W_bf    = (unsigned short*)(ws + 13107200); //  1,048,576 B
    // total ws use: 14,155,776 B

    k_prep_w<<<256, 256, 0, stream>>>(W_obj, W_bf);
    k_gemm<<<832, 64, 0, stream>>>(obj_vecs, W_bf, b_obj, att_obj);
    k_attn<<<BO / 4, 256, 0, stream>>>(att_obj, p_attr, masks, w_alpha, attr_feats, out);
}

// Round 14
// 118.973 us; speedup vs baseline: 1.0890x; 1.0890x over previous
//
#include <hip/hip_runtime.h>
#include <stdint.h>

#define EPS 1e-8f

typedef __attribute__((ext_vector_type(8))) __bf16 bf16x8;
typedef __attribute__((ext_vector_type(4))) float f32x4;

static constexpr int BO = 6400;   // B*O
static constexpr int AA = 16;     // attributes
static constexpr int DD = 1024;   // D
static constexpr int HH = 512;    // H

// ---------- helpers ----------
__device__ __forceinline__ unsigned short f2bf(float x) {
    uint32_t b = __float_as_uint(x);
    b += 0x7fffu + ((b >> 16) & 1u);   // round-to-nearest-even (finite inputs)
    return (unsigned short)(b >> 16);
}

__device__ __forceinline__ float fast_tanh(float x) {
    float e = __expf(2.0f * x);
    return 1.0f - __fdividef(2.0f, e + 1.0f);
}

// ---------- kernel 1: f32 -> bf16 staging of W_obj only ----------
__global__ __launch_bounds__(256) void k_prep_w(const float* __restrict__ W,
                                                unsigned short* __restrict__ W_bf) {
    const int i = blockIdx.x * 256 + threadIdx.x;   // 65536 8-elem units
    const long off = (long)i * 8;
    float4 v0 = *(const float4*)(W + off);
    float4 v1 = *(const float4*)(W + off + 4);
    union { unsigned short u[8]; int4 v; } pk;
    pk.u[0] = f2bf(v0.x); pk.u[1] = f2bf(v0.y); pk.u[2] = f2bf(v0.z); pk.u[3] = f2bf(v0.w);
    pk.u[4] = f2bf(v1.x); pk.u[5] = f2bf(v1.y); pk.u[6] = f2bf(v1.z); pk.u[7] = f2bf(v1.w);
    *(int4*)(W_bf + off) = pk.v;
}

// ---------- kernel 2: att_obj = obj @ W^T + b_obj, f32 out (round-3 verbatim) ----------
__global__ __launch_bounds__(64) void k_gemm(const float* __restrict__ obj,
                                             const unsigned short* __restrict__ W_bf,
                                             const float* __restrict__ b_obj,
                                             float* __restrict__ att_obj) {
    const int lane = threadIdx.x;
    const int xcd  = blockIdx.x & 7;
    const int j    = blockIdx.x >> 3;
    const int mt   = xcd * 13 + (j % 13);
    if (mt >= 100) return;
    const int nt   = j / 13;
    const int m0   = mt * 64;
    const int n0   = nt * 64;
    const int lr   = lane & 15;
    const int lk   = (lane >> 4) * 8;

    const float*          ap = obj  + (size_t)(m0 + lr) * DD + lk;
    const unsigned short* bp = W_bf + (size_t)(n0 + lr) * DD + lk;

    f32x4 acc[4][4];
    #pragma unroll
    for (int i = 0; i < 4; ++i)
        #pragma unroll
        for (int jj = 0; jj < 4; ++jj) acc[i][jj] = f32x4{0.f, 0.f, 0.f, 0.f};

    float4 a_lo[4], a_hi[4];
    bf16x8 bfr[4];
    #pragma unroll
    for (int i = 0; i < 4; ++i) {
        a_lo[i] = *(const float4*)(ap + (size_t)i * 16 * DD);
        a_hi[i] = *(const float4*)(ap + (size_t)i * 16 * DD + 4);
        bfr[i]  = *(const bf16x8*)(bp + (size_t)i * 16 * DD);
    }

    #pragma unroll 1
    for (int k0 = 0; k0 < DD; k0 += 32) {
        const int kn = (k0 + 32 < DD) ? (k0 + 32) : 0;
        float4 na_lo[4], na_hi[4];
        bf16x8 nb[4];
        #pragma unroll
        for (int i = 0; i < 4; ++i) {
            na_lo[i] = *(const float4*)(ap + (size_t)i * 16 * DD + kn);
            na_hi[i] = *(const float4*)(ap + (size_t)i * 16 * DD + kn + 4);
            nb[i]    = *(const bf16x8*)(bp + (size_t)i * 16 * DD + kn);
        }
        bf16x8 afr[4];
        #pragma unroll
        for (int i = 0; i < 4; ++i) {
            afr[i][0] = (__bf16)a_lo[i].x; afr[i][1] = (__bf16)a_lo[i].y;
            afr[i][2] = (__bf16)a_lo[i].z; afr[i][3] = (__bf16)a_lo[i].w;
            afr[i][4] = (__bf16)a_hi[i].x; afr[i][5] = (__bf16)a_hi[i].y;
            afr[i][6] = (__bf16)a_hi[i].z; afr[i][7] = (__bf16)a_hi[i].w;
        }
        #pragma unroll
        for (int i = 0; i < 4; ++i)
            #pragma unroll
            for (int jj = 0; jj < 4; ++jj)
                acc[i][jj] = __builtin_amdgcn_mfma_f32_16x16x32_bf16(afr[i], bfr[jj], acc[i][jj], 0, 0, 0);
        #pragma unroll
        for (int i = 0; i < 4; ++i) { a_lo[i] = na_lo[i]; a_hi[i] = na_hi[i]; bfr[i] = nb[i]; }
    }

    const int crow = (lane >> 4) * 4;
    #pragma unroll
    for (int jj = 0; jj < 4; ++jj) {
        const int n = n0 + jj * 16 + lr;
        const float bb = b_obj[n];
        #pragma unroll
        for (int i = 0; i < 4; ++i) {
            #pragma unroll
            for (int r = 0; r < 4; ++r)
                att_obj[(size_t)(m0 + i * 16 + crow + r) * HH + n] = acc[i][jj][r] + bb;
        }
    }
}

// ---------- kernel 3: fused attn — r12 burst-skip at MAX OCCUPANCY ----------
// ONE ROW PER 256-THREAD BLOCK (grid 6400), __launch_bounds__(256,8): 13-round
// conclusion is that occupancy was the only big lever (r10), and r12 (the best
// structure) still ran at 20/32 waves per CU. This build slims to ~56 VGPR:
//   - no w[16]: keep only mx/T/inv; recompute e=exp(sc-mx)*inv inline in pooling
//   - phase-1 bursts of 2 attrs (16 x-VGPR), phase-3 bursts of 4 (v[4])
//   - NT store for out
// Genuine mask skip retained (issued+fetched bytes ~halved). Numerics identical
// to r11/r12 (masked e=0, denom T*(1+EPS), all-masked -> exact 0).
__global__ __launch_bounds__(256, 8) void k_attn(const float* __restrict__ att_obj,   // [6400][512] f32
                                                 const float* __restrict__ p_attr,    // [6400][16][512]
                                                 const int* __restrict__ masks,       // [6400][16]
                                                 const float* __restrict__ w_alpha,   // [512]
                                                 const float* __restrict__ attr_feats,// [6400][16][1024]
                                                 float* __restrict__ out) {           // [6400][1024]
    __shared__ float s_sc[AA];

    const int tid  = threadIdx.x;
    const int wv   = tid >> 6;
    const int lane = tid & 63;
    const int row  = blockIdx.x;

    // masks -> 1-VGPR bitmask (block-uniform)
    int mbits;
    {
        const int4* m4 = (const int4*)(masks + (size_t)row * AA);
        int4 a = m4[0], b = m4[1], c = m4[2], d = m4[3];
        mbits =  (a.x)      | (a.y << 1)  | (a.z << 2)  | (a.w << 3)
              | (b.x << 4) | (b.y << 5)  | (b.z << 6)  | (b.w << 7)
              | (c.x << 8) | (c.y << 9)  | (c.z << 10) | (c.w << 11)
              | (d.x << 12)| (d.y << 13) | (d.z << 14) | (d.w << 15);
    }

    const float* prow = p_attr     + (size_t)row * AA * HH;
    const float* arow = attr_feats + (size_t)row * AA * DD;

    // ---- phase 1: wave wv scores attrs 4wv..4wv+3, two pairs; burst per pair ----
    {
        const f32x4* att4 = (const f32x4*)(att_obj + (size_t)row * HH);
        const f32x4* wa4  = (const f32x4*)w_alpha;
        const f32x4 av0 = att4[lane], av1 = att4[64 + lane];   // L1-shared by 4 waves
        const f32x4 wv0 = wa4[lane],  wv1 = wa4[64 + lane];

        #pragma unroll
        for (int pr = 0; pr < 2; ++pr) {
            const int a1 = wv * 4 + pr * 2;
            const int a2 = a1 + 1;
            const bool on1 = (mbits >> a1) & 1;
            const bool on2 = (mbits >> a2) & 1;
            f32x4 xa0, xa1, xb0, xb1;
            if (on1) {                                   // burst issue (independent)
                const f32x4* pa = (const f32x4*)(prow + (size_t)a1 * HH);
                xa0 = pa[lane]; xa1 = pa[64 + lane];
            }
            if (on2) {
                const f32x4* pb = (const f32x4*)(prow + (size_t)a2 * HH);
                xb0 = pb[lane]; xb1 = pb[64 + lane];
            }
            if (on1) {                                   // consume
                float s;
                s  = wv0.x * fast_tanh(xa0.x + av0.x);
                s += wv0.y * fast_tanh(xa0.y + av0.y);
                s += wv0.z * fast_tanh(xa0.z + av0.z);
                s += wv0.w * fast_tanh(xa0.w + av0.w);
                s += wv1.x * fast_tanh(xa1.x + av1.x);
                s += wv1.y * fast_tanh(xa1.y + av1.y);
                s += wv1.z * fast_tanh(xa1.z + av1.z);
                s += wv1.w * fast_tanh(xa1.w + av1.w);
                s += __shfl_xor(s, 1);  s += __shfl_xor(s, 2);
                s += __shfl_xor(s, 4);  s += __shfl_xor(s, 8);
                s += __shfl_xor(s, 16); s += __shfl_xor(s, 32);
                if (lane == 0) s_sc[a1] = s;
            }
            if (on2) {
                float s;
                s  = wv0.x * fast_tanh(xb0.x + av0.x);
                s += wv0.y * fast_tanh(xb0.y + av0.y);
                s += wv0.z * fast_tanh(xb0.z + av0.z);
                s += wv0.w * fast_tanh(xb0.w + av0.w);
                s += wv1.x * fast_tanh(xb1.x + av1.x);
                s += wv1.y * fast_tanh(xb1.y + av1.y);
                s += wv1.z * fast_tanh(xb1.z + av1.z);
                s += wv1.w * fast_tanh(xb1.w + av1.w);
                s += __shfl_xor(s, 1);  s += __shfl_xor(s, 2);
                s += __shfl_xor(s, 4);  s += __shfl_xor(s, 8);
                s += __shfl_xor(s, 16); s += __shfl_xor(s, 32);
                if (lane == 0) s_sc[a2] = s;
            }
        }
    }
    __syncthreads();

    // ---- phase 2: softmax params only (mx, T, inv) — no w[] array ----
    // masked slots' LDS garbage discarded by the gates; b_alpha cancels;
    // masked e == 0 -> denom = T*(1+EPS); all-masked -> inv = 0 -> out = 0 exact.
    float mx = -3.0e38f;
    #pragma unroll
    for (int a = 0; a < AA; ++a)
        mx = fmaxf(mx, (mbits >> a & 1) ? s_sc[a] : -3.0e38f);
    float T = 0.f;
    #pragma unroll
    for (int a = 0; a < AA; ++a)
        T += (mbits >> a & 1) ? __expf(s_sc[a] - mx) : 0.f;
    const float inv = (T > 0.f) ? 1.0f / (T * (1.0f + EPS)) : 0.f;

    // ---- phase 3: pooling; thread owns f32x4 slot tid; 4 quads of 4 attrs ----
    // burst the quad's loads, then gated FMAs with inline-recomputed weights
    const f32x4* af4 = (const f32x4*)arow;
    f32x4 acc = {0.f, 0.f, 0.f, 0.f};
    #pragma unroll
    for (int h = 0; h < 4; ++h) {
        f32x4 v0, v1, v2, v3;
        const int b0 = h * 4;
        if (mbits >> (b0 + 0) & 1) v0 = af4[(b0 + 0) * 256 + tid];   // burst issue
        if (mbits >> (b0 + 1) & 1) v1 = af4[(b0 + 1) * 256 + tid];
        if (mbits >> (b0 + 2) & 1) v2 = af4[(b0 + 2) * 256 + tid];
        if (mbits >> (b0 + 3) & 1) v3 = af4[(b0 + 3) * 256 + tid];
        if (mbits >> (b0 + 0) & 1) acc += (__expf(s_sc[b0 + 0] - mx) * inv) * v0;
        if (mbits >> (b0 + 1) & 1) acc += (__expf(s_sc[b0 + 1] - mx) * inv) * v1;
        if (mbits >> (b0 + 2) & 1) acc += (__expf(s_sc[b0 + 2] - mx) * inv) * v2;
        if (mbits >> (b0 + 3) & 1) acc += (__expf(s_sc[b0 + 3] - mx) * inv) * v3;
    }
    __builtin_nontemporal_store(acc, (f32x4*)(out + (size_t)row * DD + tid * 4));
}

extern "C" void kernel_launch(void* const* d_in, const int* in_sizes, int n_in,
                              void* d_out, int out_size, void* d_ws, size_t ws_size,
                              hipStream_t stream) {
    const float* obj_vecs   = (const float*)d_in[0];
    const float* attr_feats = (const float*)d_in[1];
    const float* p_attr     = (const float*)d_in[2];
    const int*   masks      = (const int*)d_in[3];
    const float* W_obj      = (const float*)d_in[4];
    const float* b_obj      = (const float*)d_in[5];
    const float* w_alpha    = (const float*)d_in[6];
    // d_in[7] = b_alpha: uniform additive shift before softmax -> cancels exactly
    float* out = (float*)d_out;

    char* ws = (char*)d_ws;
    float*          att_obj = (float*)ws;                       // 13,107,200 B
    unsigned short* W_bf    = (unsigned short*)(ws + 13107200); //  1,048,576 B
    // total ws use: 14,155,776 B

    k_prep_w<<<256, 256, 0, stream>>>(W_obj, W_bf);
    k_gemm<<<832, 64, 0, stream>>>(obj_vecs, W_bf, b_obj, att_obj);
    k_attn<<<BO, 256, 0, stream>>>(att_obj, p_attr, masks, w_alpha, attr_feats, out);
}